// Round 10
// baseline (679.566 us; speedup 1.0000x reference)
//
#include <hip/hip_runtime.h>
#include <cstdint>
#include <cmath>

#define N_HEADS 16
#define I_DIM 128
#define H_DIM 128
#define B_SZ 16
#define T_SZ 512
#define G3 384           // 3*H
#define BT (B_SZ * T_SZ) // 8192
#define LDW 136          // kernel A LDS row stride (bf16)
#define OUT_HN_OFFSET ((size_t)B_SZ * T_SZ * (N_HEADS * H_DIM)) // 16777216
#define SCHUNK 4
#define SNCHUNK (T_SZ / SCHUNK) // 128
#define HPAD2 136 // h2 row stride u16: 272B = 68 dw = 4 mod 32 banks -> 2-way (free)

typedef __attribute__((ext_vector_type(8))) short bf16x8;
typedef __attribute__((ext_vector_type(4))) float f32x4;

static __device__ __forceinline__ unsigned short f2bf(float f) {
  unsigned int u = __float_as_uint(f);
  unsigned int r = (u + 0x7FFFu + ((u >> 16) & 1u)) >> 16; // RNE
  return (unsigned short)r;
}
static __device__ __forceinline__ float bf2f(unsigned short s) {
  return __uint_as_float((unsigned int)s << 16);
}
static __device__ __forceinline__ uint2 pack4(float4 v) {
  uint2 p;
  p.x = (unsigned int)f2bf(v.x) | ((unsigned int)f2bf(v.y) << 16);
  p.y = (unsigned int)f2bf(v.z) | ((unsigned int)f2bf(v.w) << 16);
  return p;
}
static __device__ __forceinline__ bf16x8 pack8(float4 a, float4 b) {
  union { uint2 u[2]; bf16x8 v; } r;
  r.u[0] = pack4(a);
  r.u[1] = pack4(b);
  return r.v;
}

// ---------------------------------------------------------------------------
// Kernel A — proven R2 version (best measured ~120us). 1 WG/CU, full
// W_ih[n] in 104KB LDS staged once, 8 X-tiles, gates [N][BT][G3] bf16.
// ---------------------------------------------------------------------------
__global__ __launch_bounds__(256) void gates_x_mfma(
    const float* __restrict__ x, const float* __restrict__ w_ih,
    const float* __restrict__ b_ih, unsigned short* __restrict__ gates) {
  const int n = blockIdx.z;
  const int grp = blockIdx.x; // 0..15, 8 tiles of 64 bt-rows each
  const int tid = threadIdx.x;
  const int wave = tid >> 6;
  const int lane = tid & 63;
  const int m16 = lane & 15;
  const int quad = lane >> 4;

  extern __shared__ __align__(16) unsigned short lds_pool[];
  unsigned short* Ws = lds_pool;            // G3*LDW ushorts
  unsigned short* Xs = lds_pool + G3 * LDW; // 64*LDW ushorts

  const int xrow = tid >> 2;
  const int xq = tid & 3;

  float4 xf[8];
  {
    const float4* xg =
        (const float4*)(x + (size_t)(grp * 512 + xrow) * 2048 + n * I_DIM) +
        xq * 8;
#pragma unroll
    for (int i = 0; i < 8; ++i) xf[i] = xg[i];
  }

  {
    const float4* wsrc = (const float4*)(w_ih + (size_t)n * G3 * I_DIM);
#pragma unroll
    for (int i = 0; i < 48; ++i) {
      const int idx = i * 256 + tid;
      *(uint2*)&Ws[(idx >> 5) * LDW + (idx & 31) * 4] = pack4(wsrc[idx]);
    }
  }

  float bias[3][8];
#pragma unroll
  for (int gb = 0; gb < 3; ++gb)
#pragma unroll
    for (int j = 0; j < 8; ++j)
      bias[gb][j] = b_ih[n * G3 + gb * 128 + j * 16 + m16];

  for (int tile = 0; tile < 8; ++tile) {
    const int bt0 = grp * 512 + tile * 64;

    __syncthreads();
#pragma unroll
    for (int i = 0; i < 8; ++i)
      *(uint2*)&Xs[xrow * LDW + xq * 32 + i * 4] = pack4(xf[i]);
    __syncthreads();

    if (tile < 7) {
      const float4* xg =
          (const float4*)(x + (size_t)(bt0 + 64 + xrow) * 2048 + n * I_DIM) +
          xq * 8;
#pragma unroll
      for (int i = 0; i < 8; ++i) xf[i] = xg[i];
    }

#pragma unroll
    for (int gb = 0; gb < 3; ++gb) {
      f32x4 acc[8];
#pragma unroll
      for (int j = 0; j < 8; ++j) acc[j] = (f32x4){0.f, 0.f, 0.f, 0.f};

#pragma unroll
      for (int kt = 0; kt < 4; ++kt) {
        const bf16x8 afrag =
            *(const bf16x8*)&Xs[(wave * 16 + m16) * LDW + kt * 32 + quad * 8];
#pragma unroll
        for (int j = 0; j < 8; ++j) {
          const bf16x8 bfrag =
              *(const bf16x8*)&Ws[(gb * 128 + j * 16 + m16) * LDW + kt * 32 +
                                  quad * 8];
          acc[j] = __builtin_amdgcn_mfma_f32_16x16x32_bf16(afrag, bfrag,
                                                           acc[j], 0, 0, 0);
        }
      }

#pragma unroll
      for (int j = 0; j < 8; ++j) {
        const int g = gb * 128 + j * 16 + m16;
#pragma unroll
        for (int r = 0; r < 4; ++r) {
          const int bt = bt0 + wave * 16 + quad * 4 + r;
          gates[((size_t)n * BT + bt) * G3 + g] =
              f2bf(acc[j][r] + bias[gb][j]);
        }
      }
    }
  }
}

// ---------------------------------------------------------------------------
// Kernel B v8: batched-octet MFMA scan. One WG (512 thr = 8 waves) handles
// (n, 8 batches); grid = 32 (16 n x 2 octets).
//
// R9 accounting: step = MFMA 466 + VALU 550 + DS/barrier 370 (serial), and
// the MFMA D-tile used only rows 0,1 of 16 (h replicated). Fix: A-rows
// 0..15 = 8 batches x (hi,lo). Same 24 MFMA/SIMD now serve 8 chains.
// Wave w owns colblocks {w, 8+w, 16+w}; lane (w,m16,quad) holds gh for
// elem e=w*16+m16 of bb=2q (acc regs 0,1 = rows 4q,4q+1 = hi,lo) and
// bb=2q+1 (regs 2,3) IN-LANE, statically indexed: no part[], no cndmask,
// all 64 lanes update (2 updates each).
//
// h2[buf][row=2bb+p][e], row stride 136 u16 (2-way banks, free). Gates
// chunk-staged 4 steps deep (64KB dbuf), v5 flow: loads at chunk top,
// scatter before last step-barrier, out stores batched per chunk.
// Numerics identical to the R4/R5 passing path (absmax 0.0078).
// ---------------------------------------------------------------------------
__global__ __launch_bounds__(512, 1) void gru_scan_oct(
    const float* __restrict__ h0, const float* __restrict__ w_hh,
    const float* __restrict__ b_hh, const unsigned short* __restrict__ gates,
    float* __restrict__ out) {
  const int octet = blockIdx.x >> 4; // 0/1
  const int n = blockIdx.x & 15;
  const int tid = threadIdx.x;
  const int wave = tid >> 6; // 0..7
  const int lane = tid & 63;
  const int m16 = lane & 15;
  const int quad = lane >> 4;

  extern __shared__ __align__(16) unsigned short slds[];
  unsigned short* gbuf = slds;                        // [2][4][8][512] u16 = 64KB
  unsigned short* h2 = slds + 2 * SCHUNK * 8 * 512;   // [2][16][HPAD2]  u16

  // W_hh B-frags (verified layout): wave w colblocks {w, 8+w, 16+w}.
  bf16x8 wf[3][4];
  {
    const int cbs[3] = {wave, 8 + wave, 16 + wave};
#pragma unroll
    for (int j = 0; j < 3; ++j) {
      const int g = cbs[j] * 16 + m16;
      const float4* wr = (const float4*)(w_hh + ((size_t)n * G3 + g) * H_DIM);
#pragma unroll
      for (int kt = 0; kt < 4; ++kt)
        wf[j][kt] = pack8(wr[kt * 8 + quad * 2], wr[kt * 8 + quad * 2 + 1]);
    }
  }

  const int e = wave * 16 + m16; // elem updated (for both batches)
  const int bbA = 2 * quad;      // batch pair owned by this lane
  const int bbB = 2 * quad + 1;
  const int bA = octet * 8 + bbA;
  const int bB = octet * 8 + bbB;

  const float bh_r = b_hh[n * G3 + e];
  const float bh_z = b_hh[n * G3 + e + 128];
  const float bh_n = b_hh[n * G3 + e + 256];
  float hA = h0[(size_t)bA * 2048 + n * H_DIM + e];
  float hB = h0[(size_t)bB * 2048 + n * H_DIM + e];
  {
    const unsigned short a = f2bf(hA);
    h2[(4 * quad + 0) * HPAD2 + e] = a;
    h2[(4 * quad + 1) * HPAD2 + e] = f2bf(hA - bf2f(a));
    const unsigned short b2 = f2bf(hB);
    h2[(4 * quad + 2) * HPAD2 + e] = b2;
    h2[(4 * quad + 3) * HPAD2 + e] = f2bf(hB - bf2f(b2));
  }

  // ---- gates staging geometry: chunk = 32 rows (4 s x 8 bb) x 48 uint4.
  // Thread covers 3 uint4: idx = i*512+tid -> row = idx/48, col = idx%48.
  const unsigned short* gn = gates + (size_t)n * BT * G3;
  size_t gbase[3];
  int dst_i[3]; // u16 offset of (s,bb) row within one gbuf parity
  int col_i[3];
#pragma unroll
  for (int i = 0; i < 3; ++i) {
    const int idx = i * 512 + tid;
    const int row = idx / 48;
    const int col = idx - row * 48;
    const int s = row >> 3;
    const int bb = row & 7;
    gbase[i] =
        ((size_t)(octet * 8 + bb) * 512 + s) * G3 + (size_t)col * 8;
    dst_i[i] = (s * 8 + bb) * 512;
    col_i[i] = col;
  }
  uint4 pf[3];

#define LOAD_G_CHUNK(c)                                                       \
  {                                                                           \
    _Pragma("unroll") for (int i = 0; i < 3; ++i)                             \
        pf[i] = *(const uint4*)(gn + gbase[i] + (size_t)(c) * SCHUNK * G3);   \
  }

  // Scatter pf into parity p: uint4 = 8 bf16, g = col*8+k ->
  // [e2*4 + gate] with gate = g>>7, e2 = g&127.
#define SCATTER_G(p)                                                          \
  {                                                                           \
    _Pragma("unroll") for (int i = 0; i < 3; ++i) {                           \
      unsigned short* d = gbuf + (p) * (SCHUNK * 8 * 512) + dst_i[i];         \
      const unsigned int w0 = pf[i].x, w1 = pf[i].y, w2 = pf[i].z,            \
                         w3 = pf[i].w;                                        \
      const int g0 = col_i[i] * 8;                                            \
      d[((g0 + 0) & 127) * 4 + ((g0 + 0) >> 7)] = (unsigned short)w0;         \
      d[((g0 + 1) & 127) * 4 + ((g0 + 1) >> 7)] = (unsigned short)(w0 >> 16); \
      d[((g0 + 2) & 127) * 4 + ((g0 + 2) >> 7)] = (unsigned short)w1;         \
      d[((g0 + 3) & 127) * 4 + ((g0 + 3) >> 7)] = (unsigned short)(w1 >> 16); \
      d[((g0 + 4) & 127) * 4 + ((g0 + 4) >> 7)] = (unsigned short)w2;         \
      d[((g0 + 5) & 127) * 4 + ((g0 + 5) >> 7)] = (unsigned short)(w2 >> 16); \
      d[((g0 + 6) & 127) * 4 + ((g0 + 6) >> 7)] = (unsigned short)w3;         \
      d[((g0 + 7) & 127) * 4 + ((g0 + 7) >> 7)] = (unsigned short)(w3 >> 16); \
    }                                                                         \
  }

  // Prologue: chunk 0 staged into parity 0.
  LOAD_G_CHUNK(0);
  SCATTER_G(0);
  __syncthreads();

  float oA[SCHUNK], oB[SCHUNK];

  for (int c = 0; c < SNCHUNK; ++c) {
    const int gb = c & 1;

    if (c + 1 < SNCHUNK) LOAD_G_CHUNK(c + 1); // retire over this chunk

#pragma unroll
    for (int s = 0; s < SCHUNK; ++s) {
      const int rb = s & 1; // SCHUNK even -> global parity consistent
      const int wb = rb ^ 1;

      // gx for both batches: one b64 read each ({r,z,n,junk} bf16).
      const unsigned short* gsl = gbuf + gb * (SCHUNK * 8 * 512) + s * 8 * 512;
      const uint2 gA = *(const uint2*)&gsl[bbA * 512 + e * 4];
      const uint2 gB = *(const uint2*)&gsl[bbB * 512 + e * 4];
      const float gxrA = __uint_as_float(gA.x << 16);
      const float gxzA = __uint_as_float(gA.x & 0xffff0000u);
      const float gxnA = __uint_as_float(gA.y << 16);
      const float gxrB = __uint_as_float(gB.x << 16);
      const float gxzB = __uint_as_float(gB.x & 0xffff0000u);
      const float gxnB = __uint_as_float(gB.y << 16);

      // A-frags: lane supplies A-row m16 (= batch m16>>1, hi/lo by m16&1).
      const unsigned short* hsrc = h2 + rb * 16 * HPAD2 + m16 * HPAD2;
      const bf16x8 av0 = *(const bf16x8*)&hsrc[0 * 32 + quad * 8];
      const bf16x8 av1 = *(const bf16x8*)&hsrc[1 * 32 + quad * 8];
      const bf16x8 av2 = *(const bf16x8*)&hsrc[2 * 32 + quad * 8];
      const bf16x8 av3 = *(const bf16x8*)&hsrc[3 * 32 + quad * 8];

      f32x4 a0 = {0.f, 0.f, 0.f, 0.f};
      f32x4 a1 = {0.f, 0.f, 0.f, 0.f};
      f32x4 a2 = {0.f, 0.f, 0.f, 0.f};
      a0 = __builtin_amdgcn_mfma_f32_16x16x32_bf16(av0, wf[0][0], a0, 0, 0, 0);
      a1 = __builtin_amdgcn_mfma_f32_16x16x32_bf16(av0, wf[1][0], a1, 0, 0, 0);
      a2 = __builtin_amdgcn_mfma_f32_16x16x32_bf16(av0, wf[2][0], a2, 0, 0, 0);
      a0 = __builtin_amdgcn_mfma_f32_16x16x32_bf16(av1, wf[0][1], a0, 0, 0, 0);
      a1 = __builtin_amdgcn_mfma_f32_16x16x32_bf16(av1, wf[1][1], a1, 0, 0, 0);
      a2 = __builtin_amdgcn_mfma_f32_16x16x32_bf16(av1, wf[2][1], a2, 0, 0, 0);
      a0 = __builtin_amdgcn_mfma_f32_16x16x32_bf16(av2, wf[0][2], a0, 0, 0, 0);
      a1 = __builtin_amdgcn_mfma_f32_16x16x32_bf16(av2, wf[1][2], a1, 0, 0, 0);
      a2 = __builtin_amdgcn_mfma_f32_16x16x32_bf16(av2, wf[2][2], a2, 0, 0, 0);
      a0 = __builtin_amdgcn_mfma_f32_16x16x32_bf16(av3, wf[0][3], a0, 0, 0, 0);
      a1 = __builtin_amdgcn_mfma_f32_16x16x32_bf16(av3, wf[1][3], a1, 0, 0, 0);
      a2 = __builtin_amdgcn_mfma_f32_16x16x32_bf16(av3, wf[2][3], a2, 0, 0, 0);

      // Batch A (bb=2q): rows 4q,4q+1 -> regs 0,1. Batch B: regs 2,3.
      {
        const float ghr = a0[0] + a0[1] + bh_r;
        const float ghz = a1[0] + a1[1] + bh_z;
        const float ghn = a2[0] + a2[1] + bh_n;
        const float r = 1.f / (1.f + __expf(-(gxrA + ghr)));
        const float z = 1.f / (1.f + __expf(-(gxzA + ghz)));
        const float targ = gxnA + r * ghn; // bhh_n inside (in ghn)
        const float rt = 1.f / (1.f + __expf(-2.f * targ));
        const float nn = 2.f * rt - 1.f;
        const float hn = (1.f - z) * nn + z * hA;
        const unsigned short hh = f2bf(hn);
        h2[wb * 16 * HPAD2 + (4 * quad + 0) * HPAD2 + e] = hh;
        h2[wb * 16 * HPAD2 + (4 * quad + 1) * HPAD2 + e] = f2bf(hn - bf2f(hh));
        hA = hn;
        oA[s] = hn;
      }
      {
        const float ghr = a0[2] + a0[3] + bh_r;
        const float ghz = a1[2] + a1[3] + bh_z;
        const float ghn = a2[2] + a2[3] + bh_n;
        const float r = 1.f / (1.f + __expf(-(gxrB + ghr)));
        const float z = 1.f / (1.f + __expf(-(gxzB + ghz)));
        const float targ = gxnB + r * ghn;
        const float rt = 1.f / (1.f + __expf(-2.f * targ));
        const float nn = 2.f * rt - 1.f;
        const float hn = (1.f - z) * nn + z * hB;
        const unsigned short hh = f2bf(hn);
        h2[wb * 16 * HPAD2 + (4 * quad + 2) * HPAD2 + e] = hh;
        h2[wb * 16 * HPAD2 + (4 * quad + 3) * HPAD2 + e] = f2bf(hn - bf2f(hh));
        hB = hn;
        oB[s] = hn;
      }

      // Stage next chunk into the other parity before the last step-barrier.
      if (s == SCHUNK - 1 && c + 1 < SNCHUNK) SCATTER_G(gb ^ 1);
      __syncthreads();
    }

    // Batched out stores (drain amortized at next chunk's first barrier).
    {
      float* outA = out + ((size_t)bA * T_SZ + (size_t)c * SCHUNK) * 2048 +
                    n * H_DIM + e;
      float* outB = out + ((size_t)bB * T_SZ + (size_t)c * SCHUNK) * 2048 +
                    n * H_DIM + e;
#pragma unroll
      for (int s = 0; s < SCHUNK; ++s) {
        outA[(size_t)s * 2048] = oA[s];
        outB[(size_t)s * 2048] = oB[s];
      }
    }
  }

  out[OUT_HN_OFFSET + (size_t)bA * 2048 + n * H_DIM + e] = hA;
  out[OUT_HN_OFFSET + (size_t)bB * 2048 + n * H_DIM + e] = hB;
}

extern "C" void kernel_launch(void* const* d_in, const int* in_sizes, int n_in,
                              void* d_out, int out_size, void* d_ws,
                              size_t ws_size, hipStream_t stream) {
  const float* x    = (const float*)d_in[0]; // [B, T, N*I]
  const float* h0   = (const float*)d_in[1]; // [1, B, N*H]
  const float* w_ih = (const float*)d_in[2]; // [N, 3H, I]
  const float* w_hh = (const float*)d_in[3]; // [N, 3H, H]
  const float* b_ih = (const float*)d_in[4]; // [N, 3H]
  const float* b_hh = (const float*)d_in[5]; // [N, 3H]
  float* out = (float*)d_out;
  unsigned short* gates = (unsigned short*)d_ws; // [N][BT][G3] bf16 = 96 MB

  static bool lds_opt_in = false;
  if (!lds_opt_in) {
    (void)hipFuncSetAttribute(reinterpret_cast<const void*>(&gates_x_mfma),
                              hipFuncAttributeMaxDynamicSharedMemorySize,
                              (G3 + 64) * LDW * (int)sizeof(unsigned short));
    (void)hipFuncSetAttribute(reinterpret_cast<const void*>(&gru_scan_oct),
                              hipFuncAttributeMaxDynamicSharedMemorySize,
                              (2 * SCHUNK * 8 * 512 + 2 * 16 * HPAD2) *
                                  (int)sizeof(unsigned short));
    lds_opt_in = true;
  }

  dim3 gridA(16, 1, N_HEADS);
  gates_x_mfma<<<gridA, 256, (G3 + 64) * LDW * sizeof(unsigned short),
                 stream>>>(x, w_ih, b_ih, gates);
  gru_scan_oct<<<32, 512,
                 (2 * SCHUNK * 8 * 512 + 2 * 16 * HPAD2) *
                     sizeof(unsigned short),
                 stream>>>(h0, w_hh, b_hh, gates, out);
}

// Round 11
// 499.098 us; speedup vs baseline: 1.3616x; 1.3616x over previous
//
#include <hip/hip_runtime.h>
#include <cstdint>
#include <cmath>

#define N_HEADS 16
#define I_DIM 128
#define H_DIM 128
#define B_SZ 16
#define T_SZ 512
#define G3 384           // 3*H
#define OUT_HN_OFFSET ((size_t)B_SZ * T_SZ * (N_HEADS * H_DIM)) // 16777216
#define CHUNK 8
#define NCHUNK (T_SZ / CHUNK) // 64
#define HPAD 160             // h2 parity stride in ushorts (320B -> disjoint banks)

typedef __attribute__((ext_vector_type(8))) short bf16x8;
typedef __attribute__((ext_vector_type(4))) float f32x4;

static __device__ __forceinline__ unsigned short f2bf(float f) {
  unsigned int u = __float_as_uint(f);
  unsigned int r = (u + 0x7FFFu + ((u >> 16) & 1u)) >> 16; // RNE
  return (unsigned short)r;
}
static __device__ __forceinline__ float bf2f(unsigned short s) {
  return __uint_as_float((unsigned int)s << 16);
}
static __device__ __forceinline__ uint2 pack4(float4 v) {
  uint2 p;
  p.x = (unsigned int)f2bf(v.x) | ((unsigned int)f2bf(v.y) << 16);
  p.y = (unsigned int)f2bf(v.z) | ((unsigned int)f2bf(v.w) << 16);
  return p;
}
static __device__ __forceinline__ bf16x8 pack8(float4 a, float4 b) {
  union { uint2 u[2]; bf16x8 v; } r;
  r.u[0] = pack4(a);
  r.u[1] = pack4(b);
  return r.v;
}

// ---------------------------------------------------------------------------
// FUSED GRU kernel v3 = R8's PASSING kernel (359us dispatch) + one change:
// the serial chunk-top gates_x block (6 colblocks = 24 MFMA + 24 ds_write,
// ~700cy every 8 steps) is split into two 3-colblock groups carried by
// steps 0 and 4. Their MFMAs are independent of the step's gates_h chain ->
// they fill dependency-stall cycles; writes go to the OTHER gbuf parity
// (last read ended at the previous chunk's final barrier -> race-free).
//
// R10 closed the model: scan step floor ~1390cy (MFMA issue 466/SIMD +
// serial VALU/LDS/barrier); batching chains or adding waves doesn't help;
// the only reducible cost left was this serial chunk-top block.
//
// Everything else byte-identical to R8 (passed, absmax 0.0078125): CHUNK 8,
// gbuf[2][8][512] fp32, HPAD h2, n-gate bhh inside the r-product, batched
// out stores per chunk.
// ---------------------------------------------------------------------------
__global__ __launch_bounds__(256, 1) void gru_fused_kernel(
    const float* __restrict__ x, const float* __restrict__ h0,
    const float* __restrict__ w_ih, const float* __restrict__ w_hh,
    const float* __restrict__ b_ih, const float* __restrict__ b_hh,
    float* __restrict__ out) {
  const int b = blockIdx.x >> 4;
  const int n = blockIdx.x & 15;
  const int tid = threadIdx.x;
  const int wave = tid >> 6;
  const int lane = tid & 63;
  const int m16 = lane & 15;
  const int quad = lane >> 4;

  __shared__ __align__(16) unsigned short h2[2][2][HPAD]; // [buf][hi|lo]
  __shared__ __align__(16) float gbuf[2][CHUNK][512];     // [buf][s][e*4+idx]

  // ---- W_hh B-fragments (proven mapping): wave w owns colblocks
  // {2w, 8+2w, 16+2w, 2w+1, 9+2w, 17+2w} = r0,z0,n0,r1,z1,n1 for its elems.
  bf16x8 wf[6][4];
  {
    const int cb0 = 2 * wave;
    const int cbs[6] = {cb0, 8 + cb0, 16 + cb0, cb0 + 1, 9 + cb0, 17 + cb0};
#pragma unroll
    for (int j = 0; j < 6; ++j) {
      const int g = cbs[j] * 16 + m16;
      const float4* wr = (const float4*)(w_hh + ((size_t)n * G3 + g) * H_DIM);
#pragma unroll
      for (int kt = 0; kt < 4; ++kt)
        wf[j][kt] = pack8(wr[kt * 8 + quad * 2], wr[kt * 8 + quad * 2 + 1]);
    }
  }

  // ---- W_ih B-fragments: wave owns gates_x colblocks wave*6+jj (jj 0..5).
  bf16x8 wxf[6][4];
#pragma unroll
  for (int jj = 0; jj < 6; ++jj) {
    const int g = (wave * 6 + jj) * 16 + m16;
    const float4* wr = (const float4*)(w_ih + ((size_t)n * G3 + g) * I_DIM);
#pragma unroll
    for (int kt = 0; kt < 4; ++kt)
      wxf[jj][kt] = pack8(wr[kt * 8 + quad * 2], wr[kt * 8 + quad * 2 + 1]);
  }

  const bool upd = quad < 2;                    // 128 updating lanes
  const int elem = wave * 32 + quad * 16 + m16; // h element owned (if upd)

  // Biases: r/z fuse (symmetric); n-gate keeps bhh_n inside the r-product.
  float bs_r = 0.f, bs_z = 0.f, bs_n = 0.f, bh_n = 0.f, h_old = 0.f;
  if (upd) {
    bs_r = b_ih[n * G3 + elem] + b_hh[n * G3 + elem];
    bs_z = b_ih[n * G3 + elem + 128] + b_hh[n * G3 + elem + 128];
    bs_n = b_ih[n * G3 + elem + 256]; // bih_n only
    bh_n = b_hh[n * G3 + elem + 256]; // stays inside r*( . )
    h_old = h0[(size_t)b * 2048 + n * H_DIM + elem];
    const unsigned short hh = f2bf(h_old);
    h2[0][0][elem] = hh;
    h2[0][1][elem] = f2bf(h_old - bf2f(hh));
  }

  // X A-frag source: lane (m16,quad) covers row t = c*8 + (m16&7),
  // k-slice kt*32 + quad*8 .. +8 (two float4 per kt). Rows 8..15 of the
  // MFMA A-tile duplicate rows 0..7 (their D rows land in quads 2,3: unused).
  const float* xrow_base = x + (size_t)b * T_SZ * 2048 + n * I_DIM +
                           (size_t)(m16 & 7) * 2048 + quad * 8;

  float4 pf[8];  // X of the NEXT chunk to pack (in flight)
  bf16x8 af[4];  // packed A-frags of the chunk being produced

#define LOAD_X_CHUNK(c)                                                       \
  {                                                                           \
    const float* xr = xrow_base + (size_t)(c) * CHUNK * 2048;                 \
    _Pragma("unroll") for (int kt = 0; kt < 4; ++kt) {                        \
      pf[kt * 2] = *(const float4*)(xr + kt * 32);                            \
      pf[kt * 2 + 1] = *(const float4*)(xr + kt * 32 + 4);                    \
    }                                                                         \
  }

#define PACK_AF()                                                             \
  {                                                                           \
    _Pragma("unroll") for (int kt = 0; kt < 4; ++kt)                          \
        af[kt] = pack8(pf[kt * 2], pf[kt * 2 + 1]);                           \
  }

  // One gates_x colblock jj (compile-time): 4 MFMA + 4 scatter writes.
#define GATES_X_GROUP(jj, gdst)                                               \
  {                                                                           \
    f32x4 a = {0.f, 0.f, 0.f, 0.f};                                           \
    a = __builtin_amdgcn_mfma_f32_16x16x32_bf16(af[0], wxf[jj][0], a, 0, 0, 0);\
    a = __builtin_amdgcn_mfma_f32_16x16x32_bf16(af[1], wxf[jj][1], a, 0, 0, 0);\
    a = __builtin_amdgcn_mfma_f32_16x16x32_bf16(af[2], wxf[jj][2], a, 0, 0, 0);\
    a = __builtin_amdgcn_mfma_f32_16x16x32_bf16(af[3], wxf[jj][3], a, 0, 0, 0);\
    if (upd) {                                                                \
      const int g_ = (wave * 6 + (jj)) * 16 + m16;                            \
      const int e4_ = (g_ & 127) * 4 + (g_ >> 7);                             \
      (gdst)[(quad * 4 + 0) * 512 + e4_] = a[0];                              \
      (gdst)[(quad * 4 + 1) * 512 + e4_] = a[1];                              \
      (gdst)[(quad * 4 + 2) * 512 + e4_] = a[2];                              \
      (gdst)[(quad * 4 + 3) * 512 + e4_] = a[3];                              \
    }                                                                         \
  }

  // ---- prologue: chunk 0's gates_x staged (serial, once); X(1) in pf ----
  LOAD_X_CHUNK(0);
  PACK_AF();
  GATES_X_GROUP(0, &gbuf[0][0][0]);
  GATES_X_GROUP(1, &gbuf[0][0][0]);
  GATES_X_GROUP(2, &gbuf[0][0][0]);
  GATES_X_GROUP(3, &gbuf[0][0][0]);
  GATES_X_GROUP(4, &gbuf[0][0][0]);
  GATES_X_GROUP(5, &gbuf[0][0][0]);
  LOAD_X_CHUNK(1);
  __syncthreads();

  float* out_base = out + (size_t)b * T_SZ * 2048 + n * H_DIM;
  float oreg[CHUNK];

  for (int c = 0; c < NCHUNK; ++c) {
    const int gb = c & 1;

    // Chunk top: pack af = X(c+1) (~16 VALU); issue X(c+2) loads (retire
    // across this chunk's steps; drained with out stores at step-0 barrier).
    if (c + 1 < NCHUNK) {
      PACK_AF();
      if (c + 2 < NCHUNK) LOAD_X_CHUNK(c + 2);
    }

#pragma unroll
    for (int s = 0; s < CHUNK; ++s) {
      const int rb = s & 1; // chunk length even -> parity restarts at 0
      const int wb = rb ^ 1;

      // gates_x for THIS step: ONE ds_read_b128 -> {r, z, n, pad} fp32.
      float gxr = 0.f, gxz = 0.f, gxn = 0.f;
      if (upd) {
        const f32x4 g4 = *(const f32x4*)&gbuf[gb][s][elem * 4];
        gxr = g4[0];
        gxz = g4[1];
        gxn = g4[2];
      }

      // h A-fragments (hi for even m16 rows, lo for odd; HPAD bank-split).
      const unsigned short* hsrc = &h2[rb][m16 & 1][0];
      const bf16x8 av0 = *(const bf16x8*)&hsrc[0 * 32 + quad * 8];
      const bf16x8 av1 = *(const bf16x8*)&hsrc[1 * 32 + quad * 8];
      const bf16x8 av2 = *(const bf16x8*)&hsrc[2 * 32 + quad * 8];
      const bf16x8 av3 = *(const bf16x8*)&hsrc[3 * 32 + quad * 8];

      f32x4 acc[6];
#pragma unroll
      for (int j = 0; j < 6; ++j) acc[j] = (f32x4){0.f, 0.f, 0.f, 0.f};
#pragma unroll
      for (int j = 0; j < 6; ++j)
        acc[j] = __builtin_amdgcn_mfma_f32_16x16x32_bf16(av0, wf[j][0], acc[j],
                                                         0, 0, 0);
#pragma unroll
      for (int j = 0; j < 6; ++j)
        acc[j] = __builtin_amdgcn_mfma_f32_16x16x32_bf16(av1, wf[j][1], acc[j],
                                                         0, 0, 0);
#pragma unroll
      for (int j = 0; j < 6; ++j)
        acc[j] = __builtin_amdgcn_mfma_f32_16x16x32_bf16(av2, wf[j][2], acc[j],
                                                         0, 0, 0);
#pragma unroll
      for (int j = 0; j < 6; ++j)
        acc[j] = __builtin_amdgcn_mfma_f32_16x16x32_bf16(av3, wf[j][3], acc[j],
                                                         0, 0, 0);

      // Interleaved gates_x for chunk c+1: 3 colblocks at step 0, 3 at
      // step 4. Independent of this step's chain -> fills stall cycles.
      if (c + 1 < NCHUNK) {
        if (s == 0) {
          GATES_X_GROUP(0, &gbuf[gb ^ 1][0][0]);
          GATES_X_GROUP(1, &gbuf[gb ^ 1][0][0]);
          GATES_X_GROUP(2, &gbuf[gb ^ 1][0][0]);
        } else if (s == 4) {
          GATES_X_GROUP(3, &gbuf[gb ^ 1][0][0]);
          GATES_X_GROUP(4, &gbuf[gb ^ 1][0][0]);
          GATES_X_GROUP(5, &gbuf[gb ^ 1][0][0]);
        }
      }

      if (upd) {
        // D[0] = W.h_hi, D[1] = W.h_lo (rows 0,1 of each quad's 4).
        const float ghr =
            (quad ? acc[3][0] + acc[3][1] : acc[0][0] + acc[0][1]);
        const float ghz =
            (quad ? acc[4][0] + acc[4][1] : acc[1][0] + acc[1][1]);
        const float ghn0 =
            (quad ? acc[5][0] + acc[5][1] : acc[2][0] + acc[2][1]);
        const float r = 1.f / (1.f + __expf(-(gxr + ghr + bs_r)));
        const float z = 1.f / (1.f + __expf(-(gxz + ghz + bs_z)));
        // Reference ordering: n = tanh(gx_n + bih_n + r*(Wh_n + bhh_n)).
        const float targ = gxn + bs_n + r * (ghn0 + bh_n);
        const float rt = 1.f / (1.f + __expf(-2.f * targ)); // sigmoid(2x)
        const float nn = 2.f * rt - 1.f;                    // tanh(targ)
        const float hn = (1.f - z) * nn + z * h_old;
        const unsigned short hh = f2bf(hn);
        h2[wb][0][elem] = hh;
        h2[wb][1][elem] = f2bf(hn - bf2f(hh));
        h_old = hn;
        oreg[s] = hn;
      }
      __syncthreads();
    }

    // Batched out stores (drain amortized at next chunk's step-0 barrier).
    if (upd) {
#pragma unroll
      for (int s = 0; s < CHUNK; ++s)
        out_base[(size_t)(c * CHUNK + s) * 2048 + elem] = oreg[s];
    }
  }

  if (upd) {
    out[OUT_HN_OFFSET + (size_t)b * 2048 + n * H_DIM + elem] = h_old;
  }
}

extern "C" void kernel_launch(void* const* d_in, const int* in_sizes, int n_in,
                              void* d_out, int out_size, void* d_ws,
                              size_t ws_size, hipStream_t stream) {
  const float* x    = (const float*)d_in[0]; // [B, T, N*I]
  const float* h0   = (const float*)d_in[1]; // [1, B, N*H]
  const float* w_ih = (const float*)d_in[2]; // [N, 3H, I]
  const float* w_hh = (const float*)d_in[3]; // [N, 3H, H]
  const float* b_ih = (const float*)d_in[4]; // [N, 3H]
  const float* b_hh = (const float*)d_in[5]; // [N, 3H]
  float* out = (float*)d_out;
  (void)d_ws; // fused kernel: no gates workspace needed

  gru_fused_kernel<<<256, 256, 0, stream>>>(x, h0, w_ih, w_hh, b_ih, b_hh,
                                            out);
}